// Round 4
// baseline (7625.859 us; speedup 1.0000x reference)
//
#include <hip/hip_runtime.h>
#include <hip/hip_bf16.h>
#include <cstdint>

using bf16 = __hip_bfloat16;

#define Nn  512
#define Dd  10
#define Hh  256
#define Ll  128
#define CLS 140
#define ROWS 32768   // B*N
#define CH  2048     // MLP chunk rows
#define CHB (CH * 512 * 4)          // t1/t2 chunk bytes (fp32)

// out buffer element offsets
#define OUT_CLASS 1ull
#define OUT_ATOM  4587521ull
#define OUT_ADJ   4751361ull
#define ADJ_ELEMS 16777216ull

static __device__ __forceinline__ float b2f(bf16 v) { return __bfloat162float(v); }
static __device__ __forceinline__ bf16 f2b(float v) { return __float2bfloat16(v); }

// flag-based accessors (f32: 1 => buffers are fp32, 0 => bf16)
static __device__ __forceinline__ float ldF(const void* p, size_t i, int f32) {
    return f32 ? ((const float*)p)[i] : b2f(((const bf16*)p)[i]);
}
static __device__ __forceinline__ void stO(void* p, size_t i, float v, int f32) {
    if (f32) ((float*)p)[i] = v; else ((bf16*)p)[i] = f2b(v);
}
static __device__ __forceinline__ int ldM(const void* p, size_t i, int m32) {
    return m32 ? ((const int*)p)[i] : (int)(((const signed char*)p)[i]);
}
// scratch pointers inside the dead out_adj region
static __device__ __forceinline__ char* regionBase(void* out, int f32) {
    size_t es = f32 ? 4 : 2;
    return (char*)out + OUT_ADJ * es;
}
static __device__ __forceinline__ char* scratchBase(void* out, int f32) {
    return (char*)(((uintptr_t)regionBase(out, f32) + 15) & ~(uintptr_t)15);
}
static __device__ __forceinline__ float* zBase(void* out, int f32) {
    size_t es = f32 ? 4 : 2;
    uintptr_t zb = (uintptr_t)regionBase(out, f32) + ADJ_ELEMS * (es - 1) - 64;
    return (float*)((zb + 15) & ~(uintptr_t)15);
}

// ======== probe: detect input dtypes ========
__global__ __launch_bounds__(256) void probe_kernel(const void* adj, const void* nmask,
                                                    int* flags) {
    __shared__ int ok[2];
    int t = threadIdx.x;
    if (t == 0) { ok[0] = 1; ok[1] = 1; }
    __syncthreads();
    const float* a = (const float*)adj;
    const unsigned* m = (const unsigned*)nmask;
    for (int i = t; i < 2048; i += 256) {
        float v = a[i];
        if (!(v == 0.f || v == 1.f)) ok[0] = 0;
        unsigned w = m[i];
        if (!(w == 0u || w == 1u)) ok[1] = 0;
    }
    __syncthreads();
    if (t == 0) { flags[0] = ok[0]; flags[1] = ok[1]; }
}

// ======== fused encoder: agg -> h -> mu/lv -> z(fp32 scratch), KL partial ========
__global__ __launch_bounds__(256) void encoder_kernel(
    const void* __restrict__ adj, const void* __restrict__ x,
    const void* __restrict__ Wrel, const void* __restrict__ brel,
    const void* __restrict__ Wroot, const void* __restrict__ nmask,
    const void* __restrict__ Wmu, const void* __restrict__ bmu,
    const void* __restrict__ Wlv, const void* __restrict__ blv,
    const void* __restrict__ eps, void* __restrict__ outb,
    const int* __restrict__ flags, double* __restrict__ acc_kl)
{
    __shared__ float sred[11][4];
    __shared__ float ax[20];
    __shared__ float hs[256];
    __shared__ float smu[128], slv[128];
    __shared__ float sk[2];
    int f32 = flags[0], m32 = flags[1];
    float* Z = zBase(outb, f32);
    int row = blockIdx.x, t = threadIdx.x, b = row >> 9;

    float deg = 0.f, accv[10] = {};
    for (int j = t; j < Nn; j += 256) {
        float a = ldF(adj, (size_t)row * Nn + j, f32);
        if (a != 0.f) {
            deg += a;
            size_t xr = ((size_t)(b << 9) + j) * Dd;
            #pragma unroll
            for (int d = 0; d < 10; ++d) accv[d] += a * ldF(x, xr + d, f32);
        }
    }
    int lane = t & 63, wid = t >> 6;
    #pragma unroll
    for (int v = 0; v < 11; ++v) {
        float val = (v == 0) ? deg : accv[v - 1];
        #pragma unroll
        for (int o = 32; o > 0; o >>= 1) val += __shfl_xor(val, o);
        if (lane == 0) sred[v][wid] = val;
    }
    __syncthreads();
    if (t < 10) {
        float dg = fmaxf(sred[0][0] + sred[0][1] + sred[0][2] + sred[0][3], 1.f);
        ax[t] = (sred[t + 1][0] + sred[t + 1][1] + sred[t + 1][2] + sred[t + 1][3]) / dg;
    } else if (t < 20) {
        ax[t] = ldF(x, (size_t)row * Dd + (t - 10), f32);
    }
    __syncthreads();

    {
        float a = ldF(brel, t, f32);
        #pragma unroll
        for (int d = 0; d < 10; ++d)
            a += ax[d] * ldF(Wrel, d * Hh + t, f32) + ax[10 + d] * ldF(Wroot, d * Hh + t, f32);
        if (ldM(nmask, row, m32) == 0) a = 0.f;
        hs[t] = fmaxf(a, 0.f);
    }
    __syncthreads();

    {
        int col = t & 127;
        const void* W = (t < 128) ? Wmu : Wlv;
        const void* bb = (t < 128) ? bmu : blv;
        float a = ldF(bb, col, f32);
        for (int k = 0; k < 256; ++k) a = fmaf(hs[k], ldF(W, k * Ll + col, f32), a);
        if (t < 128) smu[col] = a; else slv[col] = a;
    }
    __syncthreads();

    if (t < 128) {
        float mu = smu[t], lv = slv[t];
        float e = ldF(eps, (size_t)row * Ll + t, f32);
        Z[(size_t)row * Ll + t] = mu + e * expf(0.5f * lv);
        float kt = 1.f + lv - mu * mu - expf(lv);
        #pragma unroll
        for (int o = 32; o > 0; o >>= 1) kt += __shfl_xor(kt, o);
        if ((t & 63) == 0) sk[t >> 6] = kt;
    }
    __syncthreads();
    if (t == 0) atomicAdd(acc_kl, (double)(sk[0] + sk[1]));
}

// ======== tiled GEMM on fp32 scratch: C = relu?(A @ W(bf16/f32) + bias) ========
// a_sel: 0=Z(row0), 1=t1, 2=t2 ; c_sel: 1=t1, 2=t2, 3=hx
__global__ __launch_bounds__(256) void gemm_kernel(void* __restrict__ outb,
                                                   const void* __restrict__ W,
                                                   const void* __restrict__ bias,
                                                   const int* __restrict__ flags,
                                                   int N, int K, int relu,
                                                   int a_sel, int c_sel, int row0) {
    __shared__ float As[16][64];
    __shared__ float Ws[16][64];
    int f32 = flags[0];
    char* S = scratchBase(outb, f32);
    const float* A = (a_sel == 0) ? (zBase(outb, f32) + (size_t)row0 * Ll)
                   : (a_sel == 1) ? (const float*)S : (const float*)(S + CHB);
    float* C = (c_sel == 1) ? (float*)S : (c_sel == 2) ? (float*)(S + CHB)
                                                       : (float*)(S + 2 * (size_t)CHB);
    int tid = threadIdx.x;
    int tx = tid & 15, ty = tid >> 4;
    int r0 = blockIdx.y << 6, col0 = blockIdx.x << 6;
    float acc[4][4] = {};
    int am = tid >> 2, ak = (tid & 3) << 2;
    for (int k0 = 0; k0 < K; k0 += 16) {
        float4 av = *(const float4*)&A[(size_t)(r0 + am) * K + k0 + ak];
        As[ak + 0][am] = av.x; As[ak + 1][am] = av.y;
        As[ak + 2][am] = av.z; As[ak + 3][am] = av.w;
        #pragma unroll
        for (int l = 0; l < 4; ++l) {
            int e = tid + (l << 8);
            int kk = e >> 6, nn = e & 63;
            Ws[kk][nn] = ldF(W, (size_t)(k0 + kk) * N + col0 + nn, f32);
        }
        __syncthreads();
        #pragma unroll
        for (int kk = 0; kk < 16; ++kk) {
            float4 a4 = *(const float4*)&As[kk][ty << 2];
            float4 b4 = *(const float4*)&Ws[kk][tx << 2];
            float a[4] = {a4.x, a4.y, a4.z, a4.w};
            float bb[4] = {b4.x, b4.y, b4.z, b4.w};
            #pragma unroll
            for (int i = 0; i < 4; ++i)
                #pragma unroll
                for (int j = 0; j < 4; ++j)
                    acc[i][j] = fmaf(a[i], bb[j], acc[i][j]);
        }
        __syncthreads();
    }
    #pragma unroll
    for (int i = 0; i < 4; ++i) {
        size_t m = r0 + (ty << 2) + i;
        #pragma unroll
        for (int j = 0; j < 4; ++j) {
            int nn = col0 + (tx << 2) + j;
            float v = acc[i][j] + ldF(bias, nn, f32);
            if (relu) v = fmaxf(v, 0.f);
            C[m * N + nn] = v;
        }
    }
}

// ======== conv1: z(fp32 scratch) -> c1(fp32 ws) ========
__global__ __launch_bounds__(256) void conv1_kernel(void* __restrict__ outb, int b0,
                                                    const void* __restrict__ W,
                                                    const void* __restrict__ bias,
                                                    float* __restrict__ Y,
                                                    const int* __restrict__ flags) {
    __shared__ float xs[32][129];
    __shared__ float wsh[2][32][2];
    const int Cin = 512, Tin = 128, Cout = 256, Tout = 127;
    int f32 = flags[0];
    const float* X = zBase(outb, f32) + (size_t)b0 * Nn * Ll;
    int b = blockIdx.y;
    int o0 = blockIdx.x * 2;
    int t = threadIdx.x, oy = threadIdx.y;
    int tid = oy * 128 + t;
    float acc = 0.f;
    for (int i0 = 0; i0 < Cin; i0 += 32) {
        for (int e = tid; e < 32 * Tin; e += 256) {
            int ii = e >> 7, tt = e & 127;
            xs[ii][tt] = X[((size_t)b * Cin + i0 + ii) * Tin + tt];
        }
        if (tid < 128) {
            int ol = tid >> 6, rem = tid & 63, ii = rem >> 1, k = rem & 1;
            wsh[ol][ii][k] = ldF(W, ((size_t)(o0 + ol) * Cin + i0 + ii) * 2 + k, f32);
        }
        __syncthreads();
        if (t < Tout) {
            #pragma unroll 8
            for (int ii = 0; ii < 32; ++ii)
                acc += xs[ii][t] * wsh[oy][ii][0] + xs[ii][t + 1] * wsh[oy][ii][1];
        }
        __syncthreads();
    }
    if (t < Tout)
        Y[((size_t)b * Cout + o0 + oy) * Tout + t] = fmaxf(acc + ldF(bias, o0 + oy, f32), 0.f);
}

// ======== conv2: c1(fp32) -> c2(fp32) ========
__global__ __launch_bounds__(256) void conv2_kernel(const float* __restrict__ X,
                                                    const void* __restrict__ W,
                                                    const void* __restrict__ bias,
                                                    float* __restrict__ Y,
                                                    const int* __restrict__ flags) {
    __shared__ float xs[32][128];
    __shared__ float wsh[2][32][2];
    const int Cin = 256, Tin = 127, Cout = 512, Tout = 126;
    int f32 = flags[0];
    int b = blockIdx.y;
    int o0 = blockIdx.x * 2;
    int t = threadIdx.x, oy = threadIdx.y;
    int tid = oy * 128 + t;
    float acc = 0.f;
    for (int i0 = 0; i0 < Cin; i0 += 32) {
        for (int e = tid; e < 32 * Tin; e += 256) {
            int ii = e / Tin, tt = e - ii * Tin;
            xs[ii][tt] = X[((size_t)b * Cin + i0 + ii) * Tin + tt];
        }
        if (tid < 128) {
            int ol = tid >> 6, rem = tid & 63, ii = rem >> 1, k = rem & 1;
            wsh[ol][ii][k] = ldF(W, ((size_t)(o0 + ol) * Cin + i0 + ii) * 2 + k, f32);
        }
        __syncthreads();
        if (t < Tout) {
            #pragma unroll 8
            for (int ii = 0; ii < 32; ++ii)
                acc += xs[ii][t] * wsh[oy][ii][0] + xs[ii][t + 1] * wsh[oy][ii][1];
        }
        __syncthreads();
    }
    if (t < Tout)
        Y[((size_t)b * Cout + o0 + oy) * Tout + t] = fmaxf(acc + ldF(bias, o0 + oy, f32), 0.f);
}

// ======== class head + CE ========
__global__ __launch_bounds__(256) void ce_kernel(void* __restrict__ outb,
                                                 const void* __restrict__ Wfcx,
                                                 const void* __restrict__ bfcx,
                                                 const void* __restrict__ x,
                                                 const int* __restrict__ flags,
                                                 double* __restrict__ acc_ce,
                                                 int row0) {
    __shared__ float hs[256];
    __shared__ float logits[CLS];
    __shared__ float sred[2];
    int f32 = flags[0];
    const float* hx = (const float*)(scratchBase(outb, f32) + 2 * (size_t)CHB);
    int lrow = blockIdx.x, t = threadIdx.x;
    size_t grow = (size_t)row0 + lrow;
    hs[t] = hx[(size_t)lrow * Hh + t];
    __syncthreads();
    if (t < CLS) {
        float a = ldF(bfcx, t, f32);
        for (int k = 0; k < 256; ++k) a = fmaf(hs[k], ldF(Wfcx, (size_t)k * CLS + t, f32), a);
        logits[t] = a;
        stO(outb, OUT_CLASS + grow * CLS + t, a, f32);
    }
    __syncthreads();
    if (t < 64) {
        float m = -1e30f;
        for (int j = t; j < CLS; j += 64) m = fmaxf(m, logits[j]);
        #pragma unroll
        for (int o = 32; o > 0; o >>= 1) m = fmaxf(m, __shfl_xor(m, o));
        if (t == 0) sred[0] = m;
    }
    __syncthreads();
    float maxv = sred[0];
    if (t < 64) {
        float s = 0.f;
        for (int j = t; j < CLS; j += 64) s += expf(logits[j] - maxv);
        #pragma unroll
        for (int o = 32; o > 0; o >>= 1) s += __shfl_xor(s, o);
        if (t == 0) sred[1] = s;
    }
    __syncthreads();
    if (t == 0) {
        float aa = ldF(x, grow * Dd + 0, f32);
        float ss = ldF(x, grow * Dd + 1, f32);
        int mapping = (int)((ss - 1.f) * 20.f + (aa - 1.f));
        int idx = mapping > 0 ? mapping : 0;
        float ce = -(logits[idx] - maxv - logf(sred[1]));
        if (mapping < 0) ce = 0.f;
        atomicAdd(acc_ce, (double)ce);
    }
}

// ======== atom head + MSE ========
__global__ __launch_bounds__(64) void atom_kernel(void* __restrict__ outb,
                                                  const void* __restrict__ Wfca,
                                                  const void* __restrict__ bfca,
                                                  const void* __restrict__ x,
                                                  const int* __restrict__ flags,
                                                  double* __restrict__ acc_mse,
                                                  int row0) {
    int f32 = flags[0];
    const float* ha = (const float*)(scratchBase(outb, f32) + 2 * (size_t)CHB);
    int lrow = blockIdx.x, t = threadIdx.x;
    size_t grow = (size_t)row0 + lrow;
    float acc[5] = {};
    for (int k = t; k < 256; k += 64) {
        float hv = ha[(size_t)lrow * Hh + k];
        #pragma unroll
        for (int o = 0; o < 5; ++o) acc[o] = fmaf(hv, ldF(Wfca, (size_t)k * 5 + o, f32), acc[o]);
    }
    #pragma unroll
    for (int o = 0; o < 5; ++o)
        #pragma unroll
        for (int s = 32; s > 0; s >>= 1) acc[o] += __shfl_xor(acc[o], s);
    if (t == 0) {
        float ms = 0.f;
        #pragma unroll
        for (int o = 0; o < 5; ++o) {
            float v = acc[o] + ldF(bfca, o, f32);
            stO(outb, OUT_ATOM + grow * 5 + o, v, f32);
            float d = v - ldF(x, grow * Dd + 5 + o, f32);
            ms += d * d;
        }
        atomicAdd(acc_mse, (double)ms);
    }
}

// ======== adj head + BCE ========
__global__ __launch_bounds__(256) void adjbce_kernel(const float* __restrict__ c2,
                                                     const void* __restrict__ Wfcj,
                                                     const void* __restrict__ bfcj,
                                                     const void* __restrict__ adj,
                                                     const void* __restrict__ nmask,
                                                     void* __restrict__ outb,
                                                     const int* __restrict__ flags,
                                                     double* __restrict__ acc_bce,
                                                     int b0) {
    __shared__ float cs[126];
    __shared__ float sred[4];
    int f32 = flags[0], m32 = flags[1];
    int lrow = blockIdx.x;
    size_t grow = (size_t)b0 * Nn + lrow;
    int gb = (int)(grow >> 9), n = (int)(grow & 511);
    int t = threadIdx.x;
    if (t < 126) cs[t] = c2[(size_t)lrow * 126 + t];
    __syncthreads();
    int mn = ldM(nmask, grow, m32);
    float bsum = 0.f;
    #pragma unroll
    for (int half = 0; half < 2; ++half) {
        int j = t + half * 256;
        float l = ldF(bfcj, j, f32);
        for (int k = 0; k < 126; ++k) l = fmaf(cs[k], ldF(Wfcj, (size_t)k * Nn + j, f32), l);
        stO(outb, OUT_ADJ + grow * Nn + j, l, f32);
        bool pair = (mn != 0) && (ldM(nmask, (size_t)(gb << 9) + j, m32) != 0);
        bool abin = pair && ((j == n) || (ldF(adj, grow * Nn + j, f32) > 0.f));
        bsum += fmaxf(l, 0.f) - (abin ? l : 0.f) + log1pf(expf(-fabsf(l)));
    }
    #pragma unroll
    for (int o = 32; o > 0; o >>= 1) bsum += __shfl_xor(bsum, o);
    if ((t & 63) == 0) sred[t >> 6] = bsum;
    __syncthreads();
    if (t == 0) atomicAdd(acc_bce, (double)(sred[0] + sred[1] + sred[2] + sred[3]));
}

// ======== final loss (with NaN-diagnostic sentinel) ========
__global__ void loss_kernel(const double* __restrict__ acc, void* __restrict__ outb,
                            const int* __restrict__ flags) {
    int f32 = flags[0];
    double ce  = acc[0] / 32768.0;
    double bce = acc[1] / 16777216.0;
    double mse = acc[2] / 163840.0;
    double kl  = -0.5 * acc[3];
    int bad = (!isfinite(ce) ? 1 : 0) | (!isfinite(bce) ? 2 : 0) |
              (!isfinite(mse) ? 4 : 0) | (!isfinite(kl) ? 8 : 0);
    double loss;
    if (bad) loss = 1.0e6 * bad;
    else {
        double bm = (mse != 0.0) ? fabs(ce + bce) : 0.0;  // beta*mse
        loss = ce + bm + bce + 1e-3 * kl;
    }
    stO(outb, 0, (float)loss, f32);
}

extern "C" void kernel_launch(void* const* d_in, const int* in_sizes, int n_in,
                              void* d_out, int out_size, void* d_ws, size_t ws_size,
                              hipStream_t stream) {
    const void* x      = d_in[0];
    const void* adj    = d_in[1];
    const void* nmask  = d_in[2];
    const void* eps    = d_in[3];
    const void* W_rel  = d_in[4];
    const void* b_rel  = d_in[5];
    const void* W_root = d_in[6];
    const void* W_mu   = d_in[7];
    const void* b_mu   = d_in[8];
    const void* W_lv   = d_in[9];
    const void* b_lv   = d_in[10];
    const void* Wx1    = d_in[11];
    const void* bx1    = d_in[12];
    const void* Wx2    = d_in[13];
    const void* bx2    = d_in[14];
    const void* Wx3    = d_in[15];
    const void* bx3    = d_in[16];
    const void* Wa1    = d_in[17];
    const void* ba1    = d_in[18];
    const void* Wa2    = d_in[19];
    const void* ba2    = d_in[20];
    const void* Wa3    = d_in[21];
    const void* ba3    = d_in[22];
    const void* Wc1    = d_in[23];
    const void* bc1    = d_in[24];
    const void* Wc2    = d_in[25];
    const void* bc2    = d_in[26];
    const void* W_fcx  = d_in[27];
    const void* b_fcx  = d_in[28];
    const void* W_fca  = d_in[29];
    const void* b_fca  = d_in[30];
    const void* W_fcj  = d_in[31];
    const void* b_fcj  = d_in[32];

    // d_ws: [4 doubles acc][flags at +192][conv c1/c2 fp32 from +256]
    double* acc = (double*)d_ws;
    int* flags  = (int*)((char*)d_ws + 192);
    char* S = (char*)d_ws + 256;
    size_t avail = (ws_size > 256) ? ws_size - 256 : 0;
    int NB = 64;
    while (NB > 1 && (size_t)NB * 388096 > avail) NB >>= 1;
    float* c1 = (float*)S;
    float* c2 = (float*)(S + (size_t)NB * 256 * 127 * 4);

    hipMemsetAsync(d_ws, 0, 256, stream);
    probe_kernel<<<1, 256, 0, stream>>>(adj, nmask, flags);

    encoder_kernel<<<ROWS, 256, 0, stream>>>(adj, x, W_rel, b_rel, W_root, nmask,
                                             W_mu, b_mu, W_lv, b_lv, eps, d_out,
                                             flags, acc + 3);

    // MLP chains (fp32 scratch inside out_adj region)
    for (int row0 = 0; row0 < ROWS; row0 += CH) {
        gemm_kernel<<<dim3(8, CH / 64), 256, 0, stream>>>(d_out, Wx1, bx1, flags, 512, 128, 1, 0, 1, row0);
        gemm_kernel<<<dim3(8, CH / 64), 256, 0, stream>>>(d_out, Wx2, bx2, flags, 512, 512, 1, 1, 2, 0);
        gemm_kernel<<<dim3(4, CH / 64), 256, 0, stream>>>(d_out, Wx3, bx3, flags, 256, 512, 0, 2, 3, 0);
        ce_kernel<<<CH, 256, 0, stream>>>(d_out, W_fcx, b_fcx, x, flags, acc + 0, row0);
    }
    for (int row0 = 0; row0 < ROWS; row0 += CH) {
        gemm_kernel<<<dim3(8, CH / 64), 256, 0, stream>>>(d_out, Wa1, ba1, flags, 512, 128, 1, 0, 1, row0);
        gemm_kernel<<<dim3(8, CH / 64), 256, 0, stream>>>(d_out, Wa2, ba2, flags, 512, 512, 1, 1, 2, 0);
        gemm_kernel<<<dim3(4, CH / 64), 256, 0, stream>>>(d_out, Wa3, ba3, flags, 256, 512, 0, 2, 3, 0);
        atom_kernel<<<CH, 64, 0, stream>>>(d_out, W_fca, b_fca, x, flags, acc + 2, row0);
    }

    // conv path + adj head/BCE, chunked over batches
    for (int b0 = 0; b0 < 64; b0 += NB) {
        conv1_kernel<<<dim3(128, NB), dim3(128, 2), 0, stream>>>(d_out, b0, Wc1, bc1, c1, flags);
        conv2_kernel<<<dim3(256, NB), dim3(128, 2), 0, stream>>>(c1, Wc2, bc2, c2, flags);
        adjbce_kernel<<<NB * Nn, 256, 0, stream>>>(c2, W_fcj, b_fcj, adj, nmask,
                                                   d_out, flags, acc + 1, b0);
    }

    loss_kernel<<<1, 1, 0, stream>>>(acc, d_out, flags);
}

// Round 5
// 1536.399 us; speedup vs baseline: 4.9635x; 4.9635x over previous
//
#include <hip/hip_runtime.h>
#include <hip/hip_bf16.h>
#include <cstdint>

using bf16 = __hip_bfloat16;
using bf16x8 = __attribute__((ext_vector_type(8))) __bf16;
using floatx4 = __attribute__((ext_vector_type(4))) float;

#define Nn  512
#define Dd  10
#define Hh  256
#define Ll  128
#define CLS 140
#define ROWS 32768
#define CH  16384            // MLP chunk rows (2 chunks)

// out buffer (fp32) element offsets
#define OUT_CLASS 1ull
#define OUT_ATOM  4587521ull
#define OUT_ADJ   4751361ull

// scratch byte offsets inside dead out_adj region (67,108,864 B)
// region base byte ≡ 4 (mod 16)  → +12 makes 16B-aligned
#define T1_OFF 12ull
#define T2_OFF (12ull + 16777216ull)
#define HX_OFF (12ull + 33554432ull)
#define Z_OFF  50331644ull   // region+Z_OFF ≡ 0 mod 16; end 67,108,860 <= 67,108,864

static __device__ __forceinline__ unsigned short bfb(float v) {
    __hip_bfloat16 h = __float2bfloat16(v);
    return *reinterpret_cast<unsigned short*>(&h);
}
static __device__ __forceinline__ float fbf(unsigned short u) {
    __hip_bfloat16 h = *reinterpret_cast<__hip_bfloat16*>(&u);
    return __bfloat162float(h);
}
static __device__ __forceinline__ unsigned pk2(float a, float b) {
    return (unsigned)bfb(a) | ((unsigned)bfb(b) << 16);
}

// ================= fused encoder: 8 rows/block =================
__global__ __launch_bounds__(256) void encoder_kernel(
    const float* __restrict__ adj, const float* __restrict__ x,
    const float* __restrict__ Wrel, const float* __restrict__ brel,
    const float* __restrict__ Wroot, const int* __restrict__ nmask,
    const float* __restrict__ Wmu, const float* __restrict__ bmu,
    const float* __restrict__ Wlv, const float* __restrict__ blv,
    const float* __restrict__ eps, float* __restrict__ Z,
    double* __restrict__ acc_kl)
{
    __shared__ float axs[8][20];
    __shared__ float hsm[8][256];
    __shared__ float sml[2][8][128];
    __shared__ float skred[4];
    int tid = threadIdx.x;
    int rowbase = blockIdx.x * 8;
    int b = rowbase >> 9;

    // phase 1: agg rows (group g of 32 lanes handles row g)
    {
        int g = tid >> 5, l32 = tid & 31;
        int row = rowbase + g;
        float deg = 0.f, accv[10] = {};
        for (int j = l32; j < Nn; j += 32) {
            float a = adj[(size_t)row * Nn + j];
            if (a != 0.f) {
                deg += a;
                const float* xr = x + ((size_t)(b << 9) + j) * Dd;
                #pragma unroll
                for (int d = 0; d < 10; ++d) accv[d] += a * xr[d];
            }
        }
        #pragma unroll
        for (int o = 16; o > 0; o >>= 1) {
            deg += __shfl_xor(deg, o);
            #pragma unroll
            for (int d = 0; d < 10; ++d) accv[d] += __shfl_xor(accv[d], o);
        }
        if (l32 == 0) {
            float dg = fmaxf(deg, 1.f);
            #pragma unroll
            for (int d = 0; d < 10; ++d) axs[g][d] = accv[d] / dg;
        }
        if (l32 < 10) axs[g][10 + l32] = x[(size_t)row * Dd + l32];
    }
    __syncthreads();

    // phase 2: h[r][c] for c = tid
    {
        int c = tid;
        float hacc[8];
        #pragma unroll
        for (int r = 0; r < 8; ++r) hacc[r] = brel[c];
        #pragma unroll
        for (int d = 0; d < 10; ++d) {
            float wr = Wrel[d * Hh + c], wo = Wroot[d * Hh + c];
            #pragma unroll
            for (int r = 0; r < 8; ++r)
                hacc[r] += axs[r][d] * wr + axs[r][10 + d] * wo;
        }
        #pragma unroll
        for (int r = 0; r < 8; ++r) {
            float v = (nmask[rowbase + r] != 0) ? hacc[r] : 0.f;
            hsm[r][c] = fmaxf(v, 0.f);
        }
    }
    __syncthreads();

    // phase 3: mu (half 0) / lv (half 1)
    {
        int col = tid & 127, half = tid >> 7;
        const float* W = half ? Wlv : Wmu;
        float macc[8];
        float bias = half ? blv[col] : bmu[col];
        #pragma unroll
        for (int r = 0; r < 8; ++r) macc[r] = bias;
        for (int k = 0; k < 256; ++k) {
            float w = W[k * Ll + col];
            #pragma unroll
            for (int r = 0; r < 8; ++r) macc[r] += hsm[r][k] * w;
        }
        #pragma unroll
        for (int r = 0; r < 8; ++r) sml[half][r][col] = macc[r];
    }
    __syncthreads();

    // phase 4: z + KL
    {
        float kt = 0.f;
        #pragma unroll
        for (int i = 0; i < 4; ++i) {
            int e = tid + i * 256;
            int r = e >> 7, col = e & 127;
            float mu = sml[0][r][col], lv = sml[1][r][col];
            float ee = eps[(size_t)(rowbase + r) * Ll + col];
            Z[(size_t)(rowbase + r) * Ll + col] = mu + ee * expf(0.5f * lv);
            kt += 1.f + lv - mu * mu - expf(lv);
        }
        #pragma unroll
        for (int o = 32; o > 0; o >>= 1) kt += __shfl_xor(kt, o);
        if ((tid & 63) == 0) skred[tid >> 6] = kt;
    }
    __syncthreads();
    if (tid == 0) atomicAdd(acc_kl, (double)(skred[0] + skred[1] + skred[2] + skred[3]));
}

// ================= MFMA bf16 GEMM: C[M,N](bf16) = relu?(A @ W + bias) =================
// A: fp32 (a_bf16=0) or bf16 (a_bf16=1), row-major [M][K]. W fp32 [K][N]. bias fp32.
// tile 128x128, BK=32, 256 threads = 4 waves (2x2 of 64x64).
__global__ __launch_bounds__(256) void mgemm_kernel(const void* __restrict__ A, int a_bf16,
                                                    const float* __restrict__ W,
                                                    const float* __restrict__ bias,
                                                    unsigned short* __restrict__ C,
                                                    int N, int K, int relu) {
    __shared__ uint4 AsRaw[640];   // 128 x 40 ushort
    __shared__ uint4 BsRaw[640];
    unsigned short* As = (unsigned short*)AsRaw;
    unsigned short* Bs = (unsigned short*)BsRaw;

    int tid = threadIdx.x;
    int row0 = blockIdx.y << 7, col0 = blockIdx.x << 7;
    int lane = tid & 63, wid = tid >> 6;
    int wm = (wid >> 1) * 64, wn = (wid & 1) * 64;
    int l15 = lane & 15, quad = lane >> 4;

    floatx4 acc[4][4];
    #pragma unroll
    for (int i = 0; i < 4; ++i)
        #pragma unroll
        for (int j = 0; j < 4; ++j) acc[i][j] = (floatx4){0.f, 0.f, 0.f, 0.f};

    int am = tid & 127, aseg = tid >> 7;       // A: row am, k-half aseg (16 elems)
    int bn = tid & 127, bseg = tid >> 7;       // B: col bn, k-half bseg

    for (int k0 = 0; k0 < K; k0 += 32) {
        // stage A tile (128 x 32) -> As[m][k] bf16, row pad 40
        {
            uint4* dst = (uint4*)(As + am * 40 + aseg * 16);
            if (a_bf16) {
                const uint4* ap = (const uint4*)((const unsigned short*)A +
                                   (size_t)(row0 + am) * K + k0 + aseg * 16);
                dst[0] = ap[0]; dst[1] = ap[1];
            } else {
                const float4* ap = (const float4*)((const float*)A +
                                   (size_t)(row0 + am) * K + k0 + aseg * 16);
                float4 f0 = ap[0], f1 = ap[1], f2 = ap[2], f3 = ap[3];
                uint4 v0, v1;
                v0.x = pk2(f0.x, f0.y); v0.y = pk2(f0.z, f0.w);
                v0.z = pk2(f1.x, f1.y); v0.w = pk2(f1.z, f1.w);
                v1.x = pk2(f2.x, f2.y); v1.y = pk2(f2.z, f2.w);
                v1.z = pk2(f3.x, f3.y); v1.w = pk2(f3.z, f3.w);
                dst[0] = v0; dst[1] = v1;
            }
        }
        // stage B tile (32 x 128) transposed -> Bs[n][k] bf16
        {
            unsigned r[8];
            #pragma unroll
            for (int q = 0; q < 8; ++q) {
                int kk = k0 + bseg * 16 + 2 * q;
                float w0 = W[(size_t)kk * N + col0 + bn];
                float w1 = W[(size_t)(kk + 1) * N + col0 + bn];
                r[q] = pk2(w0, w1);
            }
            uint4* dst = (uint4*)(Bs + bn * 40 + bseg * 16);
            dst[0] = (uint4){r[0], r[1], r[2], r[3]};
            dst[1] = (uint4){r[4], r[5], r[6], r[7]};
        }
        __syncthreads();

        bf16x8 af[4], bf[4];
        #pragma unroll
        for (int mt = 0; mt < 4; ++mt)
            af[mt] = __builtin_bit_cast(bf16x8,
                     *(const uint4*)(As + (wm + mt * 16 + l15) * 40 + quad * 8));
        #pragma unroll
        for (int nt = 0; nt < 4; ++nt)
            bf[nt] = __builtin_bit_cast(bf16x8,
                     *(const uint4*)(Bs + (wn + nt * 16 + l15) * 40 + quad * 8));
        #pragma unroll
        for (int mt = 0; mt < 4; ++mt)
            #pragma unroll
            for (int nt = 0; nt < 4; ++nt)
                acc[mt][nt] = __builtin_amdgcn_mfma_f32_16x16x32_bf16(
                                  af[mt], bf[nt], acc[mt][nt], 0, 0, 0);
        __syncthreads();
    }

    // epilogue
    #pragma unroll
    for (int nt = 0; nt < 4; ++nt) {
        int n = col0 + wn + nt * 16 + l15;
        float bv = bias[n];
        #pragma unroll
        for (int mt = 0; mt < 4; ++mt) {
            #pragma unroll
            for (int r = 0; r < 4; ++r) {
                int m = row0 + wm + mt * 16 + quad * 4 + r;
                float v = acc[mt][nt][r] + bv;
                if (relu) v = fmaxf(v, 0.f);
                C[(size_t)m * N + n] = bfb(v);
            }
        }
    }
}

// ================= conv as im2col fp32 GEMM: 64x64 tile =================
// Y[b][o][t] = relu(bias[o] + sum_k W[o][k] X2[k][t]), X2[k][t] = X[b][k>>1][t + (k&1)]
__global__ __launch_bounds__(256) void convgemm_kernel(const float* __restrict__ X,
                                                       const float* __restrict__ Wc,
                                                       const float* __restrict__ bias,
                                                       float* __restrict__ Y,
                                                       int Cin, int Tin, int Cout) {
    __shared__ float As[16][68];
    __shared__ float Bs[16][68];
    int K = Cin * 2, Tout = Tin - 1;
    int tid = threadIdx.x;
    int bz = blockIdx.z;
    const float* Xb = X + (size_t)bz * Cin * Tin;
    int m0 = blockIdx.y << 6, col0 = blockIdx.x << 6;
    int tx = tid & 15, ty = tid >> 4;
    float acc[4][4] = {};
    int sm = tid & 63, sks = (tid >> 6) << 2;
    int bkk = tid >> 4, btof = (tid & 15) << 2;
    for (int k0 = 0; k0 < K; k0 += 16) {
        float4 av = *(const float4*)&Wc[(size_t)(m0 + sm) * K + k0 + sks];
        As[sks + 0][sm] = av.x; As[sks + 1][sm] = av.y;
        As[sks + 2][sm] = av.z; As[sks + 3][sm] = av.w;
        {
            int kg = k0 + bkk, i = kg >> 1, par = kg & 1;
            const float* xr = Xb + (size_t)i * Tin;
            #pragma unroll
            for (int j = 0; j < 4; ++j) {
                int t = col0 + btof + j + par;
                if (t > Tin - 1) t = Tin - 1;
                Bs[bkk][btof + j] = xr[t];
            }
        }
        __syncthreads();
        #pragma unroll
        for (int kk = 0; kk < 16; ++kk) {
            float4 a4 = *(const float4*)&As[kk][ty << 2];
            float4 b4 = *(const float4*)&Bs[kk][tx << 2];
            float a[4] = {a4.x, a4.y, a4.z, a4.w};
            float bb[4] = {b4.x, b4.y, b4.z, b4.w};
            #pragma unroll
            for (int i = 0; i < 4; ++i)
                #pragma unroll
                for (int j = 0; j < 4; ++j)
                    acc[i][j] = fmaf(a[i], bb[j], acc[i][j]);
        }
        __syncthreads();
    }
    #pragma unroll
    for (int i = 0; i < 4; ++i) {
        int m = m0 + (ty << 2) + i;
        float bv = bias[m];
        #pragma unroll
        for (int j = 0; j < 4; ++j) {
            int col = col0 + (tx << 2) + j;
            if (col < Tout)
                Y[((size_t)bz * Cout + m) * Tout + col] = fmaxf(acc[i][j] + bv, 0.f);
        }
    }
}

// ================= class head + CE: 8 rows/block =================
__global__ __launch_bounds__(256) void ce_kernel(const unsigned short* __restrict__ hx,
                                                 const float* __restrict__ Wfcx,
                                                 const float* __restrict__ bfcx,
                                                 const float* __restrict__ x,
                                                 float* __restrict__ out_class,
                                                 double* __restrict__ acc_ce,
                                                 int row0) {
    __shared__ float hsm[8][256];
    __shared__ float slog[8][CLS];
    __shared__ float sce[8];
    int tid = threadIdx.x;
    int lbase = blockIdx.x * 8;
    #pragma unroll
    for (int i = 0; i < 8; ++i) {
        int e = tid + i * 256;
        int r = e >> 8, k = e & 255;
        hsm[r][k] = fbf(hx[(size_t)(lbase + r) * Hh + k]);
    }
    __syncthreads();
    for (int j = tid; j < 8 * CLS; j += 256) {
        int r = j / CLS, c = j - r * CLS;
        float a = bfcx[c];
        for (int k = 0; k < 256; ++k) a = fmaf(hsm[r][k], Wfcx[k * CLS + c], a);
        slog[r][c] = a;
        out_class[(size_t)(row0 + lbase + r) * CLS + c] = a;
    }
    __syncthreads();
    int lane = tid & 63, wid = tid >> 6;
    #pragma unroll
    for (int rr = 0; rr < 2; ++rr) {
        int r = wid * 2 + rr;
        float m = -1e30f;
        for (int j = lane; j < CLS; j += 64) m = fmaxf(m, slog[r][j]);
        #pragma unroll
        for (int o = 32; o > 0; o >>= 1) m = fmaxf(m, __shfl_xor(m, o));
        float s = 0.f;
        for (int j = lane; j < CLS; j += 64) s += expf(slog[r][j] - m);
        #pragma unroll
        for (int o = 32; o > 0; o >>= 1) s += __shfl_xor(s, o);
        if (lane == 0) {
            size_t grow = (size_t)row0 + lbase + r;
            float aa = x[grow * Dd + 0];
            float ss = x[grow * Dd + 1];
            int mapping = (int)((ss - 1.f) * 20.f + (aa - 1.f));
            int idx = mapping > 0 ? mapping : 0;
            float ce = -(slog[r][idx] - m - logf(s));
            sce[r] = (mapping < 0) ? 0.f : ce;
        }
    }
    __syncthreads();
    if (tid == 0) {
        float t = 0.f;
        #pragma unroll
        for (int r = 0; r < 8; ++r) t += sce[r];
        atomicAdd(acc_ce, (double)t);
    }
}

// ================= atom head + MSE =================
__global__ __launch_bounds__(64) void atom_kernel(const unsigned short* __restrict__ ha,
                                                  const float* __restrict__ Wfca,
                                                  const float* __restrict__ bfca,
                                                  const float* __restrict__ x,
                                                  float* __restrict__ out_atom,
                                                  double* __restrict__ acc_mse,
                                                  int row0) {
    int lrow = blockIdx.x, t = threadIdx.x;
    size_t grow = (size_t)row0 + lrow;
    float acc[5] = {};
    for (int k = t; k < 256; k += 64) {
        float hv = fbf(ha[(size_t)lrow * Hh + k]);
        #pragma unroll
        for (int o = 0; o < 5; ++o) acc[o] = fmaf(hv, Wfca[k * 5 + o], acc[o]);
    }
    #pragma unroll
    for (int o = 0; o < 5; ++o)
        #pragma unroll
        for (int s = 32; s > 0; s >>= 1) acc[o] += __shfl_xor(acc[o], s);
    if (t == 0) {
        float ms = 0.f;
        #pragma unroll
        for (int o = 0; o < 5; ++o) {
            float v = acc[o] + bfca[o];
            out_atom[grow * 5 + o] = v;
            float d = v - x[grow * Dd + 5 + o];
            ms += d * d;
        }
        atomicAdd(acc_mse, (double)ms);
    }
}

// ================= adj head + BCE: 8 rows/block =================
__global__ __launch_bounds__(256) void adjbce_kernel(const float* __restrict__ c2,
                                                     const float* __restrict__ Wfcj,
                                                     const float* __restrict__ bfcj,
                                                     const float* __restrict__ adj,
                                                     const int* __restrict__ nmask,
                                                     float* __restrict__ out_adj,
                                                     double* __restrict__ acc_bce,
                                                     int b0) {
    __shared__ float cs[8][126];
    __shared__ int smn[8];
    __shared__ float sred[4];
    int tid = threadIdx.x;
    int lbase = blockIdx.x * 8;
    size_t growbase = (size_t)b0 * Nn + lbase;
    int gb = (int)(growbase >> 9);
    for (int e = tid; e < 8 * 126; e += 256) {
        int r = e / 126, k = e - r * 126;
        cs[r][k] = c2[(size_t)(lbase + r) * 126 + k];
    }
    if (tid < 8) smn[tid] = nmask[growbase + tid];
    __syncthreads();

    int j0 = tid, j1 = tid + 256;
    float l0[8], l1[8];
    float bj0 = bfcj[j0], bj1 = bfcj[j1];
    #pragma unroll
    for (int r = 0; r < 8; ++r) { l0[r] = bj0; l1[r] = bj1; }
    for (int k = 0; k < 126; ++k) {
        float w0 = Wfcj[k * Nn + j0];
        float w1 = Wfcj[k * Nn + j1];
        #pragma unroll
        for (int r = 0; r < 8; ++r) {
            float cv = cs[r][k];
            l0[r] = fmaf(cv, w0, l0[r]);
            l1[r] = fmaf(cv, w1, l1[r]);
        }
    }
    int cm0 = nmask[(size_t)(gb << 9) + j0];
    int cm1 = nmask[(size_t)(gb << 9) + j1];
    float bsum = 0.f;
    #pragma unroll
    for (int r = 0; r < 8; ++r) {
        size_t grow = growbase + r;
        int n = (int)(grow & 511);
        int mn = smn[r];
        float a0 = adj[grow * Nn + j0];
        float a1 = adj[grow * Nn + j1];
        out_adj[grow * Nn + j0] = l0[r];
        out_adj[grow * Nn + j1] = l1[r];
        bool ab0 = (mn != 0) && (cm0 != 0) && ((j0 == n) || (a0 > 0.f));
        bool ab1 = (mn != 0) && (cm1 != 0) && ((j1 == n) || (a1 > 0.f));
        bsum += fmaxf(l0[r], 0.f) - (ab0 ? l0[r] : 0.f) + log1pf(expf(-fabsf(l0[r])));
        bsum += fmaxf(l1[r], 0.f) - (ab1 ? l1[r] : 0.f) + log1pf(expf(-fabsf(l1[r])));
    }
    #pragma unroll
    for (int o = 32; o > 0; o >>= 1) bsum += __shfl_xor(bsum, o);
    if ((tid & 63) == 0) sred[tid >> 6] = bsum;
    __syncthreads();
    if (tid == 0) atomicAdd(acc_bce, (double)(sred[0] + sred[1] + sred[2] + sred[3]));
}

// ================= final loss =================
__global__ void loss_kernel(const double* __restrict__ acc, float* __restrict__ out) {
    double ce  = acc[0] / 32768.0;
    double bce = acc[1] / 16777216.0;
    double mse = acc[2] / 163840.0;
    double kl  = -0.5 * acc[3];
    double bm = (mse != 0.0) ? fabs(ce + bce) : 0.0;   // beta*mse
    out[0] = (float)(ce + bm + bce + 1e-3 * kl);
}

extern "C" void kernel_launch(void* const* d_in, const int* in_sizes, int n_in,
                              void* d_out, int out_size, void* d_ws, size_t ws_size,
                              hipStream_t stream) {
    const float* x      = (const float*)d_in[0];
    const float* adj    = (const float*)d_in[1];
    const int*   nmask  = (const int*)d_in[2];
    const float* eps    = (const float*)d_in[3];
    const float* W_rel  = (const float*)d_in[4];
    const float* b_rel  = (const float*)d_in[5];
    const float* W_root = (const float*)d_in[6];
    const float* W_mu   = (const float*)d_in[7];
    const float* b_mu   = (const float*)d_in[8];
    const float* W_lv   = (const float*)d_in[9];
    const float* b_lv   = (const float*)d_in[10];
    const float* Wx1    = (const float*)d_in[11];
    const float* bx1    = (const float*)d_in[12];
    const float* Wx2    = (const float*)d_in[13];
    const float* bx2    = (const float*)d_in[14];
    const float* Wx3    = (const float*)d_in[15];
    const float* bx3    = (const float*)d_in[16];
    const float* Wa1    = (const float*)d_in[17];
    const float* ba1    = (const float*)d_in[18];
    const float* Wa2    = (const float*)d_in[19];
    const float* ba2    = (const float*)d_in[20];
    const float* Wa3    = (const float*)d_in[21];
    const float* ba3    = (const float*)d_in[22];
    const float* Wc1    = (const float*)d_in[23];
    const float* bc1    = (const float*)d_in[24];
    const float* Wc2    = (const float*)d_in[25];
    const float* bc2    = (const float*)d_in[26];
    const float* W_fcx  = (const float*)d_in[27];
    const float* b_fcx  = (const float*)d_in[28];
    const float* W_fca  = (const float*)d_in[29];
    const float* b_fca  = (const float*)d_in[30];
    const float* W_fcj  = (const float*)d_in[31];
    const float* b_fcj  = (const float*)d_in[32];

    float* out = (float*)d_out;
    char* region = (char*)(out + OUT_ADJ);
    unsigned short* t1 = (unsigned short*)(region + T1_OFF);
    unsigned short* t2 = (unsigned short*)(region + T2_OFF);
    unsigned short* hx = (unsigned short*)(region + HX_OFF);
    float* Z = (float*)(region + Z_OFF);

    double* acc = (double*)d_ws;
    char* S = (char*)d_ws + 256;
    size_t avail = (ws_size > 256) ? ws_size - 256 : 0;
    int NB = 64;
    while (NB > 1 && (size_t)NB * 388096 > avail) NB >>= 1;
    float* c1 = (float*)S;
    float* c2 = (float*)(S + (size_t)NB * 256 * 127 * 4);

    hipMemsetAsync(d_ws, 0, 256, stream);

    encoder_kernel<<<ROWS / 8, 256, 0, stream>>>(adj, x, W_rel, b_rel, W_root, nmask,
                                                 W_mu, b_mu, W_lv, b_lv, eps, Z, acc + 3);

    // gen_x chain
    for (int c = 0; c < 2; ++c) {
        int r0 = c * CH;
        mgemm_kernel<<<dim3(4, 128), 256, 0, stream>>>(Z + (size_t)r0 * Ll, 0, Wx1, bx1, t1, 512, 128, 1);
        mgemm_kernel<<<dim3(4, 128), 256, 0, stream>>>(t1, 1, Wx2, bx2, t2, 512, 512, 1);
        mgemm_kernel<<<dim3(2, 128), 256, 0, stream>>>(t2, 1, Wx3, bx3, hx, 256, 512, 0);
        ce_kernel<<<CH / 8, 256, 0, stream>>>(hx, W_fcx, b_fcx, x, out + OUT_CLASS, acc + 0, r0);
    }
    // gen_x_atomic chain
    for (int c = 0; c < 2; ++c) {
        int r0 = c * CH;
        mgemm_kernel<<<dim3(4, 128), 256, 0, stream>>>(Z + (size_t)r0 * Ll, 0, Wa1, ba1, t1, 512, 128, 1);
        mgemm_kernel<<<dim3(4, 128), 256, 0, stream>>>(t1, 1, Wa2, ba2, t2, 512, 512, 1);
        mgemm_kernel<<<dim3(2, 128), 256, 0, stream>>>(t2, 1, Wa3, ba3, hx, 256, 512, 0);
        atom_kernel<<<CH, 64, 0, stream>>>(hx, W_fca, b_fca, x, out + OUT_ATOM, acc + 2, r0);
    }

    // conv path + adj head/BCE, chunked over batches
    for (int b0 = 0; b0 < 64; b0 += NB) {
        convgemm_kernel<<<dim3(2, 4, NB), 256, 0, stream>>>(Z + (size_t)b0 * Nn * Ll, Wc1, bc1, c1, 512, 128, 256);
        convgemm_kernel<<<dim3(2, 8, NB), 256, 0, stream>>>(c1, Wc2, bc2, c2, 256, 127, 512);
        adjbce_kernel<<<NB * Nn / 8, 256, 0, stream>>>(c2, W_fcj, b_fcj, adj, nmask,
                                                       out + OUT_ADJ, acc + 1, b0);
    }

    loss_kernel<<<1, 1, 0, stream>>>(acc, out);
}

// Round 6
// 1310.858 us; speedup vs baseline: 5.8175x; 1.1721x over previous
//
#include <hip/hip_runtime.h>
#include <hip/hip_bf16.h>
#include <cstdint>

using bf16x8 = __attribute__((ext_vector_type(8))) __bf16;
using floatx4 = __attribute__((ext_vector_type(4))) float;
typedef unsigned short ushort;

#define Nn  512
#define Dd  10
#define Hh  256
#define Ll  128
#define CLS 140
#define ROWS 32768
#define CH  16384

// out buffer (fp32) element offsets
#define OUT_CLASS 1ull
#define OUT_ATOM  4587521ull
#define OUT_ADJ   4751361ull

// byte offsets inside dead out_adj region (67,108,864 B, base ≡ 4 mod 16)
#define T1_OFF 12ull
#define T2_OFF (12ull + 16777216ull)
#define HX_OFF (12ull + 33554432ull)
#define WT_OFF 41943068ull          // region+WT_OFF ≡ 0 mod 16
#define Z_OFF  50331644ull          // region+Z_OFF ≡ 0 mod 16

static __device__ __forceinline__ ushort bfb(float v) {
    __hip_bfloat16 h = __float2bfloat16(v);
    return *reinterpret_cast<ushort*>(&h);
}
static __device__ __forceinline__ float fbf(ushort u) {
    __hip_bfloat16 h = *reinterpret_cast<__hip_bfloat16*>(&u);
    return __bfloat162float(h);
}
static __device__ __forceinline__ unsigned pk2(float a, float b) {
    return (unsigned)bfb(a) | ((unsigned)bfb(b) << 16);
}

// ================= prep: weight convert/transpose to bf16 =================
struct PDesc { const float* src; ushort* dst; int srcR, srcC, Cp, Kp, tile0, mode; };
struct PTable { PDesc d[12]; };

__global__ __launch_bounds__(256) void prep_kernel(PTable tab) {
    __shared__ float tile[32][33];
    int bt = blockIdx.x, tid = threadIdx.x;
    int di = 0;
    #pragma unroll
    for (int i = 1; i < 12; ++i) if (bt >= tab.d[i].tile0) di = i;
    PDesc d = tab.d[di];
    int lt = bt - d.tile0;
    if (d.mode == 1) {  // plain convert
        long base = (long)lt * 8192;
        const float* s = d.src;
        ushort* o = d.dst;
        for (int i = tid; i < 2048; i += 256) {
            long idx = base + (long)i * 4;
            float4 v = *(const float4*)&s[idx];
            unsigned u0 = pk2(v.x, v.y), u1 = pk2(v.z, v.w);
            *(uint2*)&o[idx] = (uint2){u0, u1};
        }
        return;
    }
    int tilesK = (d.Kp + 31) >> 5;
    int k0 = (lt % tilesK) << 5, n0 = (lt / tilesK) << 5;
    int tx = tid & 31, ty = tid >> 5;
    for (int ky = ty; ky < 32; ky += 8) {
        int k = k0 + ky, n = n0 + tx;
        float v = (k < d.srcR && n < d.srcC) ? d.src[(size_t)k * d.srcC + n] : 0.f;
        tile[ky][tx] = v;
    }
    __syncthreads();
    for (int ny = ty; ny < 32; ny += 8) {
        int n = n0 + ny, k = k0 + tx;
        if (n < d.Cp && k < d.Kp) d.dst[(size_t)n * d.Kp + k] = bfb(tile[tx][ny]);
    }
}

// ================= encoder v3: 16 rows/block, MFMA mu/lv =================
__global__ __launch_bounds__(256) void encoder_kernel(
    const float* __restrict__ adj, const float* __restrict__ x,
    const float* __restrict__ Wrel, const float* __restrict__ brel,
    const float* __restrict__ Wroot, const int* __restrict__ nmask,
    const ushort* __restrict__ Wtmu, const float* __restrict__ bmu,
    const ushort* __restrict__ Wtlv, const float* __restrict__ blv,
    const float* __restrict__ eps, float* __restrict__ Z,
    double* __restrict__ acc_kl)
{
    __shared__ float u0[5120];            // phase0/1: xs[512][10]; phase3/4: sml[2][16][128]
    __shared__ ushort hsb[16 * 264];
    __shared__ float axs[16][20];
    __shared__ float skred[4];
    int tid = threadIdx.x;
    int rowbase = blockIdx.x * 16;
    int b = rowbase >> 9, rowloc = rowbase & 511;

    // phase 0: stage x[b] into LDS
    for (int e = tid; e < 5120; e += 256) u0[e] = x[(size_t)b * 5120 + e];
    __syncthreads();

    // phase 1: agg; 16 groups of 16 lanes
    {
        int g = tid >> 4, l16 = tid & 15;
        size_t arow = (size_t)(rowbase + g) * Nn;
        float deg = 0.f, accv[10] = {};
        for (int j = l16; j < Nn; j += 16) {
            float a = adj[arow + j];
            if (a != 0.f) {
                deg += a;
                const float* xr = &u0[j * 10];
                #pragma unroll
                for (int d = 0; d < 10; ++d) accv[d] += a * xr[d];
            }
        }
        #pragma unroll
        for (int o = 8; o > 0; o >>= 1) {
            deg += __shfl_xor(deg, o);
            #pragma unroll
            for (int d = 0; d < 10; ++d) accv[d] += __shfl_xor(accv[d], o);
        }
        if (l16 == 0) {
            float dg = fmaxf(deg, 1.f);
            #pragma unroll
            for (int d = 0; d < 10; ++d) axs[g][d] = accv[d] / dg;
        }
        if (l16 < 10) axs[g][10 + l16] = u0[(rowloc + g) * 10 + l16];
    }
    __syncthreads();

    // phase 2: h -> bf16 LDS (MFMA A layout rows)
    {
        int c = tid;
        float hacc[16];
        float bb = brel[c];
        #pragma unroll
        for (int r = 0; r < 16; ++r) hacc[r] = bb;
        #pragma unroll
        for (int d = 0; d < 10; ++d) {
            float wr = Wrel[d * Hh + c], wo = Wroot[d * Hh + c];
            #pragma unroll
            for (int r = 0; r < 16; ++r)
                hacc[r] += axs[r][d] * wr + axs[r][10 + d] * wo;
        }
        #pragma unroll
        for (int r = 0; r < 16; ++r) {
            float v = (nmask[rowbase + r] != 0) ? hacc[r] : 0.f;
            hsb[r * 264 + c] = bfb(fmaxf(v, 0.f));
        }
    }
    __syncthreads();

    // phase 3: mu/lv via MFMA (M=16 rows, N=128, K=256)
    {
        int lane = tid & 63, wid = tid >> 6;
        int l15 = lane & 15, quad = lane >> 4;
        int half = wid >> 1;                       // 0=mu, 1=lv
        const ushort* Wt = half ? Wtlv : Wtmu;
        const float* bv = half ? blv : bmu;
        #pragma unroll
        for (int i = 0; i < 4; ++i) {
            int ct = (wid & 1) * 4 + i;
            floatx4 a = (floatx4){0.f, 0.f, 0.f, 0.f};
            #pragma unroll
            for (int k0 = 0; k0 < 8; ++k0) {
                bf16x8 af = __builtin_bit_cast(bf16x8,
                    *(const uint4*)(hsb + l15 * 264 + k0 * 32 + quad * 8));
                bf16x8 bfr = __builtin_bit_cast(bf16x8,
                    *(const uint4*)(Wt + (size_t)(ct * 16 + l15) * 256 + k0 * 32 + quad * 8));
                a = __builtin_amdgcn_mfma_f32_16x16x32_bf16(af, bfr, a, 0, 0, 0);
            }
            int col = ct * 16 + l15;
            float bvv = bv[col];
            #pragma unroll
            for (int r4 = 0; r4 < 4; ++r4) {
                int r = quad * 4 + r4;
                u0[half * 2048 + r * 128 + col] = a[r4] + bvv;
            }
        }
    }
    __syncthreads();

    // phase 4: z + KL
    {
        float kt = 0.f;
        #pragma unroll
        for (int i = 0; i < 8; ++i) {
            int e = tid + i * 256;
            float mu = u0[e], lv = u0[2048 + e];
            float ee = eps[(size_t)rowbase * Ll + e];
            Z[(size_t)rowbase * Ll + e] = mu + ee * expf(0.5f * lv);
            kt += 1.f + lv - mu * mu - expf(lv);
        }
        #pragma unroll
        for (int o = 32; o > 0; o >>= 1) kt += __shfl_xor(kt, o);
        if ((tid & 63) == 0) skred[tid >> 6] = kt;
    }
    __syncthreads();
    if (tid == 0) atomicAdd(acc_kl, (double)(skred[0] + skred[1] + skred[2] + skred[3]));
}

// ================= unified MFMA GEMM: C = relu?(A @ Bt^T + bias) =================
// A row-major [M][K] fp32 or bf16; Bt bf16 [N][K]; C bf16 or fp32, row stride ldc.
__global__ __launch_bounds__(256) void mgemm_kernel(const void* __restrict__ A, int a_bf16,
                                                    const ushort* __restrict__ Bt,
                                                    const float* __restrict__ bias,
                                                    void* __restrict__ Cp, int c_fp32,
                                                    int N, int K, int ldc, int relu) {
    __shared__ uint4 AsRaw[640];
    __shared__ uint4 BsRaw[640];
    ushort* As = (ushort*)AsRaw;
    ushort* Bs = (ushort*)BsRaw;
    int tid = threadIdx.x;
    int row0 = blockIdx.y << 7, col0 = blockIdx.x << 7;
    int lane = tid & 63, wid = tid >> 6;
    int wm = (wid >> 1) * 64, wn = (wid & 1) * 64;
    int l15 = lane & 15, quad = lane >> 4;
    floatx4 acc[4][4];
    #pragma unroll
    for (int i = 0; i < 4; ++i)
        #pragma unroll
        for (int j = 0; j < 4; ++j) acc[i][j] = (floatx4){0.f, 0.f, 0.f, 0.f};
    int am = tid & 127, aseg = tid >> 7;
    for (int k0 = 0; k0 < K; k0 += 32) {
        {
            uint4* dst = (uint4*)(As + am * 40 + aseg * 16);
            if (a_bf16) {
                const uint4* ap = (const uint4*)((const ushort*)A + (size_t)(row0 + am) * K + k0 + aseg * 16);
                dst[0] = ap[0]; dst[1] = ap[1];
            } else {
                const float4* ap = (const float4*)((const float*)A + (size_t)(row0 + am) * K + k0 + aseg * 16);
                float4 f0 = ap[0], f1 = ap[1], f2 = ap[2], f3 = ap[3];
                dst[0] = (uint4){pk2(f0.x, f0.y), pk2(f0.z, f0.w), pk2(f1.x, f1.y), pk2(f1.z, f1.w)};
                dst[1] = (uint4){pk2(f2.x, f2.y), pk2(f2.z, f2.w), pk2(f3.x, f3.y), pk2(f3.z, f3.w)};
            }
        }
        {
            const uint4* bp = (const uint4*)(Bt + (size_t)(col0 + am) * K + k0 + aseg * 16);
            uint4* dst = (uint4*)(Bs + am * 40 + aseg * 16);
            dst[0] = bp[0]; dst[1] = bp[1];
        }
        __syncthreads();
        bf16x8 af[4], bfv[4];
        #pragma unroll
        for (int mt = 0; mt < 4; ++mt)
            af[mt] = __builtin_bit_cast(bf16x8, *(const uint4*)(As + (wm + mt * 16 + l15) * 40 + quad * 8));
        #pragma unroll
        for (int nt = 0; nt < 4; ++nt)
            bfv[nt] = __builtin_bit_cast(bf16x8, *(const uint4*)(Bs + (wn + nt * 16 + l15) * 40 + quad * 8));
        #pragma unroll
        for (int mt = 0; mt < 4; ++mt)
            #pragma unroll
            for (int nt = 0; nt < 4; ++nt)
                acc[mt][nt] = __builtin_amdgcn_mfma_f32_16x16x32_bf16(af[mt], bfv[nt], acc[mt][nt], 0, 0, 0);
        __syncthreads();
    }
    #pragma unroll
    for (int nt = 0; nt < 4; ++nt) {
        int n = col0 + wn + nt * 16 + l15;
        float bv = bias[n];
        #pragma unroll
        for (int mt = 0; mt < 4; ++mt)
            #pragma unroll
            for (int r = 0; r < 4; ++r) {
                size_t m = row0 + wm + mt * 16 + quad * 4 + r;
                float v = acc[mt][nt][r] + bv;
                if (relu) v = fmaxf(v, 0.f);
                if (c_fp32) ((float*)Cp)[m * ldc + n] = v;
                else ((ushort*)Cp)[m * ldc + n] = bfb(v);
            }
    }
}

// ================= conv (K=2, VALID, relu) as MFMA GEMM =================
// Y[bz][m][t] = relu(bias[m] + sum_k Ab[m][k]*X[k>>1][t+(k&1)]); Y stride 128, cols>=Tout zeroed.
__global__ __launch_bounds__(256) void convmfma_kernel(const void* __restrict__ X, int x_bf16,
                                                       long xBS,
                                                       const ushort* __restrict__ Ab,
                                                       const float* __restrict__ bias,
                                                       ushort* __restrict__ Y,
                                                       int Cout, int K, int Tout) {
    __shared__ uint4 AsRaw[640];
    __shared__ uint4 BsRaw[640];
    ushort* As = (ushort*)AsRaw;
    ushort* Bs = (ushort*)BsRaw;
    int tid = threadIdx.x, bz = blockIdx.z;
    int row0 = blockIdx.y << 7;
    int lane = tid & 63, wid = tid >> 6;
    int wm = (wid >> 1) * 64, wn = (wid & 1) * 64;
    int l15 = lane & 15, quad = lane >> 4;
    floatx4 acc[4][4];
    #pragma unroll
    for (int i = 0; i < 4; ++i)
        #pragma unroll
        for (int j = 0; j < 4; ++j) acc[i][j] = (floatx4){0.f, 0.f, 0.f, 0.f};
    int am = tid & 127, aseg = tid >> 7;
    int tnext = (am + 1 > 127) ? 127 : am + 1;
    for (int k0 = 0; k0 < K; k0 += 32) {
        {
            const uint4* ap = (const uint4*)(Ab + (size_t)(row0 + am) * K + k0 + aseg * 16);
            uint4* dst = (uint4*)(As + am * 40 + aseg * 16);
            dst[0] = ap[0]; dst[1] = ap[1];
        }
        {
            unsigned r[8];
            if (x_bf16) {
                const ushort* Xb = (const ushort*)X + (size_t)bz * xBS;
                #pragma unroll
                for (int q = 0; q < 8; ++q) {
                    int kk = k0 + aseg * 16 + 2 * q, i = kk >> 1;
                    r[q] = (unsigned)Xb[i * 128 + am] | ((unsigned)Xb[i * 128 + tnext] << 16);
                }
            } else {
                const float* Xf = (const float*)X + (size_t)bz * xBS;
                #pragma unroll
                for (int q = 0; q < 8; ++q) {
                    int kk = k0 + aseg * 16 + 2 * q, i = kk >> 1;
                    r[q] = pk2(Xf[i * 128 + am], Xf[i * 128 + tnext]);
                }
            }
            uint4* dst = (uint4*)(Bs + am * 40 + aseg * 16);
            dst[0] = (uint4){r[0], r[1], r[2], r[3]};
            dst[1] = (uint4){r[4], r[5], r[6], r[7]};
        }
        __syncthreads();
        bf16x8 af[4], bfv[4];
        #pragma unroll
        for (int mt = 0; mt < 4; ++mt)
            af[mt] = __builtin_bit_cast(bf16x8, *(const uint4*)(As + (wm + mt * 16 + l15) * 40 + quad * 8));
        #pragma unroll
        for (int nt = 0; nt < 4; ++nt)
            bfv[nt] = __builtin_bit_cast(bf16x8, *(const uint4*)(Bs + (wn + nt * 16 + l15) * 40 + quad * 8));
        #pragma unroll
        for (int mt = 0; mt < 4; ++mt)
            #pragma unroll
            for (int nt = 0; nt < 4; ++nt)
                acc[mt][nt] = __builtin_amdgcn_mfma_f32_16x16x32_bf16(af[mt], bfv[nt], acc[mt][nt], 0, 0, 0);
        __syncthreads();
    }
    #pragma unroll
    for (int mt = 0; mt < 4; ++mt)
        #pragma unroll
        for (int r = 0; r < 4; ++r) {
            int m = row0 + wm + mt * 16 + quad * 4 + r;
            float bv = bias[m];
            #pragma unroll
            for (int nt = 0; nt < 4; ++nt) {
                int col = wn + nt * 16 + l15;
                float v = fmaxf(acc[mt][nt][r] + bv, 0.f);
                if (col >= Tout) v = 0.f;
                Y[((size_t)bz * Cout + m) * 128 + col] = bfb(v);
            }
        }
}

// ================= class head + CE (MFMA, 16 rows/block) =================
__global__ __launch_bounds__(256) void ce_kernel(const ushort* __restrict__ hx,
                                                 const ushort* __restrict__ Wt,
                                                 const float* __restrict__ bfcx,
                                                 const float* __restrict__ x,
                                                 float* __restrict__ out_class,
                                                 double* __restrict__ acc_ce,
                                                 int row0) {
    __shared__ ushort hxb[16 * 264];
    __shared__ float slog[16][144];
    __shared__ float sce[16];
    int tid = threadIdx.x;
    int lbase = blockIdx.x * 16;
    for (int e = tid; e < 512; e += 256) {
        int r = e >> 5, seg = e & 31;
        *(uint4*)(hxb + r * 264 + seg * 8) = *(const uint4*)(hx + (size_t)(lbase + r) * 256 + seg * 8);
    }
    __syncthreads();
    int lane = tid & 63, wid = tid >> 6, l15 = lane & 15, quad = lane >> 4;
    for (int ct = wid; ct < 9; ct += 4) {
        floatx4 a = (floatx4){0.f, 0.f, 0.f, 0.f};
        #pragma unroll
        for (int k0 = 0; k0 < 8; ++k0) {
            bf16x8 af = __builtin_bit_cast(bf16x8, *(const uint4*)(hxb + l15 * 264 + k0 * 32 + quad * 8));
            bf16x8 bfr = __builtin_bit_cast(bf16x8, *(const uint4*)(Wt + (size_t)(ct * 16 + l15) * 256 + k0 * 32 + quad * 8));
            a = __builtin_amdgcn_mfma_f32_16x16x32_bf16(af, bfr, a, 0, 0, 0);
        }
        int col = ct * 16 + l15;
        float bv = (col < CLS) ? bfcx[col] : 0.f;
        #pragma unroll
        for (int r4 = 0; r4 < 4; ++r4) {
            int r = quad * 4 + r4;
            float v = a[r4] + bv;
            slog[r][col] = v;
            if (col < CLS) out_class[(size_t)(row0 + lbase + r) * CLS + col] = v;
        }
    }
    __syncthreads();
    #pragma unroll
    for (int rr = 0; rr < 4; ++rr) {
        int r = wid * 4 + rr;
        float m = -1e30f;
        for (int j = lane; j < CLS; j += 64) m = fmaxf(m, slog[r][j]);
        #pragma unroll
        for (int o = 32; o > 0; o >>= 1) m = fmaxf(m, __shfl_xor(m, o));
        float s = 0.f;
        for (int j = lane; j < CLS; j += 64) s += expf(slog[r][j] - m);
        #pragma unroll
        for (int o = 32; o > 0; o >>= 1) s += __shfl_xor(s, o);
        if (lane == 0) {
            size_t grow = (size_t)row0 + lbase + r;
            float aa = x[grow * Dd + 0];
            float ss = x[grow * Dd + 1];
            int mapping = (int)((ss - 1.f) * 20.f + (aa - 1.f));
            int idx = mapping > 0 ? mapping : 0;
            float ce = -(slog[r][idx] - m - logf(s));
            sce[r] = (mapping < 0) ? 0.f : ce;
        }
    }
    __syncthreads();
    if (tid == 0) {
        float t = 0.f;
        #pragma unroll
        for (int r = 0; r < 16; ++r) t += sce[r];
        atomicAdd(acc_ce, (double)t);
    }
}

// ================= atom head + MSE =================
__global__ __launch_bounds__(64) void atom_kernel(const ushort* __restrict__ ha,
                                                  const float* __restrict__ Wfca,
                                                  const float* __restrict__ bfca,
                                                  const float* __restrict__ x,
                                                  float* __restrict__ out_atom,
                                                  double* __restrict__ acc_mse,
                                                  int row0) {
    int lrow = blockIdx.x, t = threadIdx.x;
    size_t grow = (size_t)row0 + lrow;
    float acc[5] = {};
    for (int k = t; k < 256; k += 64) {
        float hv = fbf(ha[(size_t)lrow * Hh + k]);
        #pragma unroll
        for (int o = 0; o < 5; ++o) acc[o] = fmaf(hv, Wfca[k * 5 + o], acc[o]);
    }
    #pragma unroll
    for (int o = 0; o < 5; ++o)
        #pragma unroll
        for (int s = 32; s > 0; s >>= 1) acc[o] += __shfl_xor(acc[o], s);
    if (t == 0) {
        float ms = 0.f;
        #pragma unroll
        for (int o = 0; o < 5; ++o) {
            float v = acc[o] + bfca[o];
            out_atom[grow * 5 + o] = v;
            float d = v - x[grow * Dd + 5 + o];
            ms += d * d;
        }
        atomicAdd(acc_mse, (double)ms);
    }
}

// ================= elementwise BCE over out_adj =================
__global__ __launch_bounds__(256) void bce_kernel(const float* __restrict__ out_adj,
                                                  const float* __restrict__ adj,
                                                  const int* __restrict__ nmask,
                                                  double* __restrict__ acc_bce) {
    __shared__ float sred[4];
    int tid = threadIdx.x;
    float bsum = 0.f;
    for (size_t e = (size_t)blockIdx.x * 256 + tid; e < 16777216ull; e += (size_t)gridDim.x * 256) {
        float l = out_adj[e];
        size_t grow = e >> 9;
        int col = (int)(e & 511);
        int gb = (int)(grow >> 9), n = (int)(grow & 511);
        int mn = nmask[grow];
        int cm = nmask[(size_t)gb * 512 + col];
        float a = adj[e];
        bool abin = (mn != 0) && (cm != 0) && ((col == n) || (a > 0.f));
        bsum += fmaxf(l, 0.f) - (abin ? l : 0.f) + log1pf(expf(-fabsf(l)));
    }
    #pragma unroll
    for (int o = 32; o > 0; o >>= 1) bsum += __shfl_xor(bsum, o);
    if ((tid & 63) == 0) sred[tid >> 6] = bsum;
    __syncthreads();
    if (tid == 0) atomicAdd(acc_bce, (double)(sred[0] + sred[1] + sred[2] + sred[3]));
}

// ======== FALLBACK (small ws): R5 fp32 conv + fused adj/BCE ========
__global__ __launch_bounds__(256) void convgemm_kernel(const float* __restrict__ X,
                                                       const float* __restrict__ Wc,
                                                       const float* __restrict__ bias,
                                                       float* __restrict__ Y,
                                                       int Cin, int Tin, int Cout) {
    __shared__ float As[16][68];
    __shared__ float Bs[16][68];
    int K = Cin * 2, Tout = Tin - 1;
    int tid = threadIdx.x, bz = blockIdx.z;
    const float* Xb = X + (size_t)bz * Cin * Tin;
    int m0 = blockIdx.y << 6, col0 = blockIdx.x << 6;
    int tx = tid & 15, ty = tid >> 4;
    float acc[4][4] = {};
    int sm = tid & 63, sks = (tid >> 6) << 2;
    int bkk = tid >> 4, btof = (tid & 15) << 2;
    for (int k0 = 0; k0 < K; k0 += 16) {
        float4 av = *(const float4*)&Wc[(size_t)(m0 + sm) * K + k0 + sks];
        As[sks + 0][sm] = av.x; As[sks + 1][sm] = av.y;
        As[sks + 2][sm] = av.z; As[sks + 3][sm] = av.w;
        {
            int kg = k0 + bkk, i = kg >> 1, par = kg & 1;
            const float* xr = Xb + (size_t)i * Tin;
            #pragma unroll
            for (int j = 0; j < 4; ++j) {
                int t = col0 + btof + j + par;
                if (t > Tin - 1) t = Tin - 1;
                Bs[bkk][btof + j] = xr[t];
            }
        }
        __syncthreads();
        #pragma unroll
        for (int kk = 0; kk < 16; ++kk) {
            float4 a4 = *(const float4*)&As[kk][ty << 2];
            float4 b4 = *(const float4*)&Bs[kk][tx << 2];
            float a[4] = {a4.x, a4.y, a4.z, a4.w};
            float bb[4] = {b4.x, b4.y, b4.z, b4.w};
            #pragma unroll
            for (int i = 0; i < 4; ++i)
                #pragma unroll
                for (int j = 0; j < 4; ++j)
                    acc[i][j] = fmaf(a[i], bb[j], acc[i][j]);
        }
        __syncthreads();
    }
    #pragma unroll
    for (int i = 0; i < 4; ++i) {
        int m = m0 + (ty << 2) + i;
        float bv = bias[m];
        #pragma unroll
        for (int j = 0; j < 4; ++j) {
            int col = col0 + (tx << 2) + j;
            if (col < Tout)
                Y[((size_t)bz * Cout + m) * Tout + col] = fmaxf(acc[i][j] + bv, 0.f);
        }
    }
}

__global__ __launch_bounds__(256) void adjbce_kernel(const float* __restrict__ c2,
                                                     const float* __restrict__ Wfcj,
                                                     const float* __restrict__ bfcj,
                                                     const float* __restrict__ adj,
                                                     const int* __restrict__ nmask,
                                                     float* __restrict__ out_adj,
                                                     double* __restrict__ acc_bce,
                                                     int b0) {
    __shared__ float cs[8][126];
    __shared__ int smn[8];
    __shared__ float sred[4];
    int tid = threadIdx.x;
    int lbase = blockIdx.x * 8;
    size_t growbase = (size_t)b0 * Nn + lbase;
    int gb = (int)(growbase >> 9);
    for (int e = tid; e < 8 * 126; e += 256) {
        int r = e / 126, k = e - r * 126;
        cs[r][k] = c2[(size_t)(lbase + r) * 126 + k];
    }
    if (tid < 8) smn[tid] = nmask[growbase + tid];
    __syncthreads();
    int j0 = tid, j1 = tid + 256;
    float l0[8], l1[8];
    float bj0 = bfcj[j0], bj1 = bfcj[j1];
    #pragma unroll
    for (int r = 0; r < 8; ++r) { l0[r] = bj0; l1[r] = bj1; }
    for (int k = 0; k < 126; ++k) {
        float w0 = Wfcj[k * Nn + j0];
        float w1 = Wfcj[k * Nn + j1];
        #pragma unroll
        for (int r = 0; r < 8; ++r) {
            float cv = cs[r][k];
            l0[r] = fmaf(cv, w0, l0[r]);
            l1[r] = fmaf(cv, w1, l1[r]);
        }
    }
    int cm0 = nmask[(size_t)(gb << 9) + j0];
    int cm1 = nmask[(size_t)(gb << 9) + j1];
    float bsum = 0.f;
    #pragma unroll
    for (int r = 0; r < 8; ++r) {
        size_t grow = growbase + r;
        int n = (int)(grow & 511);
        int mn = smn[r];
        float a0 = adj[grow * Nn + j0];
        float a1 = adj[grow * Nn + j1];
        out_adj[grow * Nn + j0] = l0[r];
        out_adj[grow * Nn + j1] = l1[r];
        bool ab0 = (mn != 0) && (cm0 != 0) && ((j0 == n) || (a0 > 0.f));
        bool ab1 = (mn != 0) && (cm1 != 0) && ((j1 == n) || (a1 > 0.f));
        bsum += fmaxf(l0[r], 0.f) - (ab0 ? l0[r] : 0.f) + log1pf(expf(-fabsf(l0[r])));
        bsum += fmaxf(l1[r], 0.f) - (ab1 ? l1[r] : 0.f) + log1pf(expf(-fabsf(l1[r])));
    }
    #pragma unroll
    for (int o = 32; o > 0; o >>= 1) bsum += __shfl_xor(bsum, o);
    if ((tid & 63) == 0) sred[tid >> 6] = bsum;
    __syncthreads();
    if (tid == 0) atomicAdd(acc_bce, (double)(sred[0] + sred[1] + sred[2] + sred[3]));
}

// ================= final loss =================
__global__ void loss_kernel(const double* __restrict__ acc, float* __restrict__ out) {
    double ce  = acc[0] / 32768.0;
    double bce = acc[1] / 16777216.0;
    double mse = acc[2] / 163840.0;
    double kl  = -0.5 * acc[3];
    double bm = (mse != 0.0) ? fabs(ce + bce) : 0.0;   // beta*mse
    out[0] = (float)(ce + bm + bce + 1e-3 * kl);
}

extern "C" void kernel_launch(void* const* d_in, const int* in_sizes, int n_in,
                              void* d_out, int out_size, void* d_ws, size_t ws_size,
                              hipStream_t stream) {
    const float* x      = (const float*)d_in[0];
    const float* adj    = (const float*)d_in[1];
    const int*   nmask  = (const int*)d_in[2];
    const float* eps    = (const float*)d_in[3];
    const float* W_rel  = (const float*)d_in[4];
    const float* b_rel  = (const float*)d_in[5];
    const float* W_root = (const float*)d_in[6];
    const float* W_mu   = (const float*)d_in[7];
    const float* b_mu   = (const float*)d_in[8];
    const float* W_lv   = (const float*)d_in[9];
    const float* b_lv   = (const float*)d_in[10];
    const float* Wx1    = (const float*)d_in[11];
    const float* bx1    = (const float*)d_in[12];
    const float* Wx2    = (const float*)d_in[13];
    const float* bx2    = (const float*)d_in[14];
    const float* Wx3    = (const float*)d_in[15];
    const float* bx3    = (const float*)d_in[16];
    const float* Wa1    = (const float*)d_in[17];
    const float* ba1    = (const float*)d_in[18];
    const float* Wa2    = (const float*)d_in[19];
    const float* ba2    = (const float*)d_in[20];
    const float* Wa3    = (const float*)d_in[21];
    const float* ba3    = (const float*)d_in[22];
    const float* Wc1    = (const float*)d_in[23];
    const float* bc1    = (const float*)d_in[24];
    const float* Wc2    = (const float*)d_in[25];
    const float* bc2    = (const float*)d_in[26];
    const float* W_fcx  = (const float*)d_in[27];
    const float* b_fcx  = (const float*)d_in[28];
    const float* W_fca  = (const float*)d_in[29];
    const float* b_fca  = (const float*)d_in[30];
    const float* W_fcj  = (const float*)d_in[31];
    const float* b_fcj  = (const float*)d_in[32];

    float* out = (float*)d_out;
    char* region = (char*)(out + OUT_ADJ);
    ushort* t1 = (ushort*)(region + T1_OFF);
    ushort* t2 = (ushort*)(region + T2_OFF);
    ushort* hx = (ushort*)(region + HX_OFF);
    float*  Z  = (float*)(region + Z_OFF);

    // MLP-phase weights in region (dead before conv phase)
    ushort* wt_x1  = (ushort*)(region + WT_OFF);
    ushort* wt_x2  = wt_x1 + 65536;
    ushort* wt_x3  = wt_x2 + 262144;
    ushort* wt_a1  = wt_x3 + 131072;
    ushort* wt_a2  = wt_a1 + 65536;
    ushort* wt_a3  = wt_a2 + 262144;
    ushort* wt_mu  = wt_a3 + 131072;
    ushort* wt_lv  = wt_mu + 32768;
    ushort* wt_fcx = wt_lv + 32768;

    // conv-phase weights + buffers in d_ws
    double* acc = (double*)d_ws;
    ushort* wc1b   = (ushort*)((char*)d_ws + 256);
    ushort* wc2b   = wc1b + 262144;
    ushort* wt_fcj = wc2b + 262144;
    char* convbuf = (char*)d_ws + 1179904;
    bool fastConv = ws_size >= (size_t)1179904 + 196608;

    hipMemsetAsync(d_ws, 0, 256, stream);

    // ---- prep table ----
    PTable tab;
    int t0 = 0;
    auto setT = [&](int i, const float* s, ushort* d, int R, int C, int Cp, int Kp) {
        tab.d[i] = {s, d, R, C, Cp, Kp, t0, 0};
        t0 += ((Cp + 31) / 32) * ((Kp + 31) / 32);
    };
    setT(0, Wx1, wt_x1, 128, 512, 512, 128);
    setT(1, Wx2, wt_x2, 512, 512, 512, 512);
    setT(2, Wx3, wt_x3, 512, 256, 256, 512);
    setT(3, Wa1, wt_a1, 128, 512, 512, 128);
    setT(4, Wa2, wt_a2, 512, 512, 512, 512);
    setT(5, Wa3, wt_a3, 512, 256, 256, 512);
    setT(6, W_mu, wt_mu, 256, 128, 128, 256);
    setT(7, W_lv, wt_lv, 256, 128, 128, 256);
    setT(8, W_fcx, wt_fcx, 256, 140, 144, 256);
    setT(9, W_fcj, wt_fcj, 126, 512, 512, 128);
    tab.d[10] = {Wc1, wc1b, 262144, 0, 0, 0, t0, 1}; t0 += 32;
    tab.d[11] = {Wc2, wc2b, 262144, 0, 0, 0, t0, 1}; t0 += 32;
    if (!fastConv) { tab.d[9].src = W_mu; tab.d[9].dst = wt_mu; tab.d[10] = tab.d[9]; tab.d[11] = tab.d[9];
                     tab.d[9].mode = 0; tab.d[10].tile0 = t0 + 999; tab.d[11].tile0 = t0 + 999; t0 = tab.d[9].tile0; }
    prep_kernel<<<fastConv ? 1128 : 960, 256, 0, stream>>>(tab);

    encoder_kernel<<<ROWS / 16, 256, 0, stream>>>(adj, x, W_rel, b_rel, W_root, nmask,
                                                  wt_mu, b_mu, wt_lv, b_lv, eps, Z, acc + 3);

    // ---- MLP chains ----
    for (int c = 0; c < 2; ++c) {
        int r0 = c * CH;
        mgemm_kernel<<<dim3(4, 128), 256, 0, stream>>>(Z + (size_t)r0 * Ll, 0, wt_x1, bx1, t1, 0, 512, 128, 512, 1);
        mgemm_kernel<<<dim3(4, 128), 256, 0, stream>>>(t1, 1, wt_x2, bx2, t2, 0, 512, 512, 512, 1);
        mgemm_kernel<<<dim3(2, 128), 256, 0, stream>>>(t2, 1, wt_x3, bx3, hx, 0, 256, 512, 256, 0);
        ce_kernel<<<CH / 16, 256, 0, stream>>>(hx, wt_fcx, b_fcx, x, out + OUT_CLASS, acc + 0, r0);
    }
    for (int c = 0; c < 2; ++c) {
        int r0 = c * CH;
        mgemm_kernel<<<dim3(4, 128), 256, 0, stream>>>(Z + (size_t)r0 * Ll, 0, wt_a1, ba1, t1, 0, 512, 128, 512, 1);
        mgemm_kernel<<<dim3(4, 128), 256, 0, stream>>>(t1, 1, wt_a2, ba2, t2, 0, 512, 512, 512, 1);
        mgemm_kernel<<<dim3(2, 128), 256, 0, stream>>>(t2, 1, wt_a3, ba3, hx, 0, 256, 512, 256, 0);
        atom_kernel<<<CH, 64, 0, stream>>>(hx, W_fca, b_fca, x, out + OUT_ATOM, acc + 2, r0);
    }

    // ---- conv path + adj head ----
    if (fastConv) {
        size_t avail = ws_size - 1179904;
        int NB = 64;
        while (NB > 1 && (size_t)NB * 196608 > avail) NB >>= 1;
        ushort* c1 = (ushort*)convbuf;
        ushort* c2 = c1 + (size_t)NB * 32768;
        for (int b0 = 0; b0 < 64; b0 += NB) {
            convmfma_kernel<<<dim3(1, 2, NB), 256, 0, stream>>>(Z + (size_t)b0 * 65536, 0, 65536,
                                                               wc1b, bc1, c1, 256, 1024, 127);
            convmfma_kernel<<<dim3(1, 4, NB), 256, 0, stream>>>(c1, 1, 32768,
                                                               wc2b, bc2, c2, 512, 512, 126);
            mgemm_kernel<<<dim3(4, NB * 4), 256, 0, stream>>>(c2, 1, wt_fcj, b_fcj,
                                                              out + OUT_ADJ + (size_t)b0 * 262144, 1,
                                                              512, 128, 512, 0);
        }
        bce_kernel<<<1024, 256, 0, stream>>>(out + OUT_ADJ, adj, nmask, acc + 1);
    } else {
        size_t avail = (ws_size > 256) ? ws_size - 256 : 0;
        int NB = 64;
        while (NB > 1 && (size_t)NB * 388096 > avail) NB >>= 1;
        float* c1 = (float*)((char*)d_ws + 256);
        float* c2 = (float*)((char*)d_ws + 256 + (size_t)NB * 256 * 127 * 4);
        for (int b0 = 0; b0 < 64; b0 += NB) {
            convgemm_kernel<<<dim3(2, 4, NB), 256, 0, stream>>>(Z + (size_t)b0 * 65536, Wc1, bc1, c1, 512, 128, 256);
            convgemm_kernel<<<dim3(2, 8, NB), 256, 0, stream>>>(c1, Wc2, bc2, c2, 256, 127, 512);
            adjbce_kernel<<<NB * Nn / 8, 256, 0, stream>>>(c2, W_fcj, b_fcj, adj, nmask,
                                                           out + OUT_ADJ, acc + 1, b0);
        }
    }

    loss_kernel<<<1, 1, 0, stream>>>(acc, out);
}